// Round 11
// baseline (177.048 us; speedup 1.0000x reference)
//
#include <hip/hip_runtime.h>

// Problem constants: B=2, S=4096, H=8, DH=64, D=512, M = B*S = 8192.
#define LOG2E 1.44269504088896340736f

typedef unsigned short u16;
typedef __bf16 bf16x4_t __attribute__((ext_vector_type(4)));
typedef __bf16 bf16x8_t __attribute__((ext_vector_type(8)));
typedef float f32x4_t __attribute__((ext_vector_type(4)));

__device__ __forceinline__ f32x4_t mfma16(bf16x8_t a, bf16x8_t b, f32x4_t c) {
  return __builtin_amdgcn_mfma_f32_16x16x32_bf16(a, b, c, 0, 0, 0);
}

// async 16B global -> LDS (dest = wave-uniform base + lane*16)
__device__ __forceinline__ void gl_lds16(const u16* g, u16* l) {
  __builtin_amdgcn_global_load_lds(
      (const __attribute__((address_space(1))) unsigned int*)g,
      (__attribute__((address_space(3))) unsigned int*)l, 16, 0, 0);
}

// ---------------- one-shot cast: fp32 -> bf16 (Wq pre-scaled by 0.125*log2e) --------------
__global__ __launch_bounds__(256) void cast_kernel(
    const float* __restrict__ x, const float* __restrict__ Wq, const float* __restrict__ Wk,
    const float* __restrict__ Wv, const float* __restrict__ Wo,
    u16* __restrict__ Xb, u16* __restrict__ Wqb, u16* __restrict__ Wkb,
    u16* __restrict__ Wvb, u16* __restrict__ Wob) {
  const int bid = blockIdx.x;
  const float* src;
  u16* dst;
  float scale = 1.f;
  int rel;
  if (bid < 2048)      { src = x;  dst = Xb;  rel = bid; }
  else if (bid < 2176) { src = Wq; dst = Wqb; rel = bid - 2048; scale = 0.125f * LOG2E; }
  else if (bid < 2304) { src = Wk; dst = Wkb; rel = bid - 2176; }
  else if (bid < 2432) { src = Wv; dst = Wvb; rel = bid - 2304; }
  else                 { src = Wo; dst = Wob; rel = bid - 2432; }
  const int i = rel * 2048 + threadIdx.x * 8;
  f32x4_t a = *(const f32x4_t*)(src + i) * scale;
  f32x4_t b = *(const f32x4_t*)(src + i + 4) * scale;
  union { uint4 u; struct { bf16x4_t lo, hi; } s; } c;
  c.s.lo = __builtin_convertvector(a, bf16x4_t);
  c.s.hi = __builtin_convertvector(b, bf16x4_t);
  *(uint4*)(dst + i) = c.u;
}

// ---------------- fused QKV GEMM v3: 64x128 tile, double-buffered K-loop ------------------
// grid (128,4), 512 threads. LDS 112KB = 2 bufs x {As[64][64] + Bq/Bk/Bv[128][64]}.
// T3-minimum 2-phase: stage tile t+1 into buf^1 BEFORE computing tile t -> the end-of-iter
// barrier's vmcnt(0) drain waits on loads that had a full compute phase in flight.
__global__ __launch_bounds__(512) void gemm_qkv_fused(
    const u16* __restrict__ Xb,
    const u16* __restrict__ Wqb, const u16* __restrict__ Wkb, const u16* __restrict__ Wvb,
    u16* __restrict__ Q, u16* __restrict__ K, u16* __restrict__ Vt) {
  __shared__ __align__(16) u16 SM[57344];  // 112KB; buf stride 28672 u16
  const int t = threadIdx.x;
  const int wave = t >> 6, lane = t & 63;
  const int r = lane & 15, qd = lane >> 4;
  const int wn = wave;  // 8 waves x 16 cols = 128
  const int rr = lane >> 3;
  const int s8 = ((lane & 7) ^ (rr & 7)) * 8;  // pre-swizzled global 16B slot
  const int Mbase = blockIdx.x * 64, Nbase = blockIdx.y * 128;

  f32x4_t acc[3][4];
#pragma unroll
  for (int w = 0; w < 3; w++)
#pragma unroll
    for (int i = 0; i < 4; i++) { f32x4_t z = {0.f, 0.f, 0.f, 0.f}; acc[w][i] = z; }

  const u16* pa = Xb  + (Mbase + wave * 8 + rr) * 512 + s8;
  const u16* pq = Wqb + (Nbase + wave * 16 + rr) * 512 + s8;
  const u16* pk = Wkb + (Nbase + wave * 16 + rr) * 512 + s8;
  const u16* pv = Wvb + (Nbase + wave * 16 + rr) * 512 + s8;
  // per-wave staging bases within a buffer (u16 offsets)
  u16* la = SM + wave * 512;           // As[wave*8][0]
  u16* lq = SM + 4096 + wave * 1024;   // Bq[wave*16][0]
  u16* lk = SM + 12288 + wave * 1024;
  u16* lv = SM + 20480 + wave * 1024;

#define QKV_STAGE(KO, BOFF)                                         \
  do {                                                              \
    gl_lds16(pa + (KO), la + (BOFF));                               \
    _Pragma("unroll") for (int p = 0; p < 2; p++) {                 \
      gl_lds16(pq + (KO) + p * 8 * 512, lq + (BOFF) + p * 512);     \
      gl_lds16(pk + (KO) + p * 8 * 512, lk + (BOFF) + p * 512);     \
      gl_lds16(pv + (KO) + p * 8 * 512, lv + (BOFF) + p * 512);     \
    }                                                               \
  } while (0)

  QKV_STAGE(0, 0);
  __syncthreads();

  for (int kt = 0; kt < 8; kt++) {
    const int cb = (kt & 1) * 28672;
    const int nb = ((kt + 1) & 1) * 28672;
    if (kt < 7) QKV_STAGE((kt + 1) * 64, nb);
    const u16* As = SM + cb;
    const u16* Bq = SM + cb + 4096;
    const u16* Bk = SM + cb + 12288;
    const u16* Bv = SM + cb + 20480;
#pragma unroll
    for (int h = 0; h < 2; h++) {
      const int cs = ((h * 4 + qd) ^ (r & 7)) * 8;
      bf16x8_t af[4];
#pragma unroll
      for (int i = 0; i < 4; i++) af[i] = *(const bf16x8_t*)&As[(i * 16 + r) * 64 + cs];
      bf16x8_t fq = *(const bf16x8_t*)&Bq[(wn * 16 + r) * 64 + cs];
      bf16x8_t fk = *(const bf16x8_t*)&Bk[(wn * 16 + r) * 64 + cs];
      bf16x8_t fv = *(const bf16x8_t*)&Bv[(wn * 16 + r) * 64 + cs];
#pragma unroll
      for (int i = 0; i < 4; i++) {
        acc[0][i] = mfma16(af[i], fq, acc[0][i]);
        acc[1][i] = mfma16(af[i], fk, acc[1][i]);
        acc[2][i] = mfma16(af[i], fv, acc[2][i]);
      }
    }
    __syncthreads();  // drains stage(kt+1); guards buffer reuse
  }
#undef QKV_STAGE

  // ---------------- epilogue: LDS-transpose, coalesced stores ----------------
#pragma unroll
  for (int w = 0; w < 2; w++) {
    __syncthreads();
    u16* dst = (w == 0) ? Q : K;
#pragma unroll
    for (int i = 0; i < 4; i++)
#pragma unroll
      for (int reg = 0; reg < 4; reg++) {
        int row = i * 16 + qd * 4 + reg;       // 0..63
        int col = wn * 16 + r;                 // 0..127
        __bf16 bvv = (__bf16)acc[w][i][reg];
        SM[row * 128 + (col ^ (((row >> 2) & 7) << 3))] = *(u16*)&bvv;
      }
    __syncthreads();
#pragma unroll
    for (int p = 0; p < 2; p++) {
      int row = p * 32 + (t >> 4);
      int col = (t & 15) * 8;
      uint4 v = *(const uint4*)&SM[row * 128 + (col ^ (((row >> 2) & 7) << 3))];
      *(uint4*)&dst[(Mbase + row) * 512 + Nbase + col] = v;
    }
  }
  // V: stage transposed [d][s] (128x64) so the V^T store is coalesced along s
  __syncthreads();
#pragma unroll
  for (int i = 0; i < 4; i++)
#pragma unroll
    for (int reg = 0; reg < 4; reg++) {
      int srow = i * 16 + qd * 4 + reg;        // s within tile, 0..63
      int dcol = wn * 16 + r;                  // d within tile, 0..127
      __bf16 bvv = (__bf16)acc[2][i][reg];
      SM[dcol * 64 + (srow ^ (((dcol >> 2) & 7) << 3))] = *(u16*)&bvv;
    }
  __syncthreads();
  {
    const int bb = Mbase >> 12;
    const int smod = Mbase & 4095;
#pragma unroll
    for (int p = 0; p < 2; p++) {
      int d = p * 64 + (t >> 3);
      int scol = (t & 7) * 8;
      uint4 v = *(const uint4*)&SM[d * 64 + (scol ^ (((d >> 2) & 7) << 3))];
      *(uint4*)&Vt[((long)(bb * 512 + Nbase + d)) * 4096 + smod + scol] = v;
    }
  }
}

// ---------------- out-proj GEMM v3: 64x128 tile, double-buffered, 3 blocks/CU -------------
__global__ __launch_bounds__(512) void gemm_out_kernel(
    const u16* __restrict__ Aat, const u16* __restrict__ Wob,
    float* __restrict__ Out, const float* __restrict__ bo) {
  __shared__ __align__(16) u16 SM[24576];  // 48KB; buf stride 12288 u16 (As 4096 + Bs 8192)
  const int t = threadIdx.x;
  const int wave = t >> 6, lane = t & 63;
  const int r = lane & 15, qd = lane >> 4;
  const int wn = wave;
  const int rr = lane >> 3;
  const int s8 = ((lane & 7) ^ (rr & 7)) * 8;
  const int Mbase = blockIdx.x * 64, Nbase = blockIdx.y * 128;

  f32x4_t acc[4];
#pragma unroll
  for (int i = 0; i < 4; i++) { f32x4_t z = {0.f, 0.f, 0.f, 0.f}; acc[i] = z; }

  const u16* pa = Aat + (Mbase + wave * 8 + rr) * 512 + s8;
  const u16* pb = Wob + (Nbase + wave * 16 + rr) * 512 + s8;
  u16* la = SM + wave * 512;          // As[wave*8][0]
  u16* lb = SM + 4096 + wave * 1024;  // Bs[wave*16][0]

#define OUT_STAGE(KO, BOFF)                                          \
  do {                                                               \
    gl_lds16(pa + (KO), la + (BOFF));                                \
    _Pragma("unroll") for (int p = 0; p < 2; p++)                    \
      gl_lds16(pb + (KO) + p * 8 * 512, lb + (BOFF) + p * 512);      \
  } while (0)

  OUT_STAGE(0, 0);
  __syncthreads();

  for (int kt = 0; kt < 8; kt++) {
    const int cb = (kt & 1) * 12288;
    const int nb = ((kt + 1) & 1) * 12288;
    if (kt < 7) OUT_STAGE((kt + 1) * 64, nb);
    const u16* As = SM + cb;
    const u16* Bs = SM + cb + 4096;
#pragma unroll
    for (int h = 0; h < 2; h++) {
      const int cs = ((h * 4 + qd) ^ (r & 7)) * 8;
      bf16x8_t af[4];
#pragma unroll
      for (int i = 0; i < 4; i++) af[i] = *(const bf16x8_t*)&As[(i * 16 + r) * 64 + cs];
      bf16x8_t bfr = *(const bf16x8_t*)&Bs[(wn * 16 + r) * 64 + cs];
#pragma unroll
      for (int i = 0; i < 4; i++) acc[i] = mfma16(af[i], bfr, acc[i]);
    }
    __syncthreads();
  }
#undef OUT_STAGE

  float* stf = (float*)SM;  // 64x128 f32 = 32KB (fits in 48KB)
  float bv = bo[Nbase + wn * 16 + r];
#pragma unroll
  for (int i = 0; i < 4; i++)
#pragma unroll
    for (int reg = 0; reg < 4; reg++) {
      int row = i * 16 + qd * 4 + reg;   // 0..63
      int col = wn * 16 + r;             // 0..127
      stf[row * 128 + (col ^ (((row >> 2) & 7) << 2))] = acc[i][reg] + bv;
    }
  __syncthreads();
#pragma unroll
  for (int p = 0; p < 4; p++) {
    int row = p * 16 + (t >> 5);
    int col4 = (t & 31) * 4;
    f32x4_t v = *(const f32x4_t*)&stf[row * 128 + (col4 ^ (((row >> 2) & 7) << 2))];
    *(f32x4_t*)&Out[(Mbase + row) * 512 + Nbase + col4] = v;
  }
}

// ---------------- flash attention v7 + setprio (best measured: 82.0 us) -------------------
__global__ __launch_bounds__(256, 2) void attn_kernel(
    const u16* __restrict__ Q, const u16* __restrict__ K, const u16* __restrict__ Vt,
    u16* __restrict__ Oattn) {
  __shared__ __align__(16) u16 Ks[2][2][4096];
  __shared__ __align__(16) u16 Vs[2][2][4096];

  const int t = threadIdx.x;
  const int wave = t >> 6, lane = t & 63;
  const int r = lane & 15, qd = lane >> 4;
  const int g = wave & 1, kv = wave >> 1;
  const int bh = blockIdx.y;
  const int b = bh >> 3, h = bh & 7;
  const long bbase = (long)b * 4096 * 512;
  const int q0 = blockIdx.x * 128;

  const int sw = r & 7;
  const int ck0 = (qd ^ sw) * 8;
  const int ck1 = ((qd + 4) ^ sw) * 8;
  int vo0[2], vo1[2];
#pragma unroll
  for (int c = 0; c < 2; c++) {
    vo0[c] = ((c * 4 + (qd >> 1)) ^ sw) * 8 + 4 * (qd & 1);
    vo1[c] = ((c * 4 + 2 + (qd >> 1)) ^ sw) * 8 + 4 * (qd & 1);
  }

  bf16x8_t ones8;
#pragma unroll
  for (int j = 0; j < 8; j++) ones8[j] = (__bf16)1.0f;

  bf16x8_t qf[4][2];
#pragma unroll
  for (int qa = 0; qa < 4; qa++) {
    const u16* qp = Q + bbase + (long)(q0 + g * 64 + qa * 16 + r) * 512 + h * 64 + qd * 8;
    qf[qa][0] = *(const bf16x8_t*)(qp);
    qf[qa][1] = *(const bf16x8_t*)(qp + 32);
  }

  f32x4_t accO[4][4];
  f32x4_t accL[4];
#pragma unroll
  for (int qa = 0; qa < 4; qa++) {
    f32x4_t z = {0.f, 0.f, 0.f, 0.f};
    accL[qa] = z;
#pragma unroll
    for (int nt = 0; nt < 4; nt++) accO[qa][nt] = z;
  }

  const int rr = lane >> 3;
  const int cc = (lane & 7) ^ rr;
  const u16* kgb = K + bbase + (long)(kv * 2048 + g * 32 + rr) * 512 + h * 64 + cc * 8;
  const u16* vgb = Vt + ((long)(b * 512 + h * 64 + g * 32 + rr)) * 4096 + kv * 2048 + cc * 8;

#pragma unroll
  for (int i = 0; i < 4; i++) gl_lds16(kgb + (long)i * 8 * 512, &Ks[kv][0][g * 2048] + i * 512);
#pragma unroll
  for (int i = 0; i < 4; i++) gl_lds16(vgb + i * 8 * 4096, &Vs[kv][0][g * 2048] + i * 512);

  for (int it = 0; it < 32; it++) {
    const int buf = it & 1;
    __syncthreads();

    if (it < 31) {
      const int nb = (it + 1) & 1;
      const long ko = (long)(it + 1) * 64;
#pragma unroll
      for (int i = 0; i < 4; i++)
        gl_lds16(kgb + (ko + i * 8) * 512, &Ks[kv][nb][g * 2048] + i * 512);
#pragma unroll
      for (int i = 0; i < 4; i++)
        gl_lds16(vgb + ko + (long)i * 8 * 4096, &Vs[kv][nb][g * 2048] + i * 512);
    }

    bf16x8_t kf[4][2];
#pragma unroll
    for (int nt = 0; nt < 4; nt++) {
      const u16* kb = &Ks[kv][buf][(nt * 16 + r) * 64];
      kf[nt][0] = *(const bf16x8_t*)(kb + ck0);
      kf[nt][1] = *(const bf16x8_t*)(kb + ck1);
    }

    f32x4_t St[4][4];
    __builtin_amdgcn_s_setprio(1);
#pragma unroll
    for (int qa = 0; qa < 4; qa++)
#pragma unroll
      for (int nt = 0; nt < 4; nt++) {
        f32x4_t z = {0.f, 0.f, 0.f, 0.f};
        z = mfma16(kf[nt][0], qf[qa][0], z);
        z = mfma16(kf[nt][1], qf[qa][1], z);
        St[qa][nt] = z;
      }
    __builtin_amdgcn_s_setprio(0);

    bf16x8_t pf[4][2];
#pragma unroll
    for (int qa = 0; qa < 4; qa++)
#pragma unroll
      for (int c = 0; c < 2; c++) {
        f32x4_t e0, e1;
#pragma unroll
        for (int j = 0; j < 4; j++) {
          e0[j] = __builtin_amdgcn_exp2f(St[qa][2 * c][j]);
          e1[j] = __builtin_amdgcn_exp2f(St[qa][2 * c + 1][j]);
        }
        bf16x4_t b0 = __builtin_convertvector(e0, bf16x4_t);
        bf16x4_t b1 = __builtin_convertvector(e1, bf16x4_t);
        bf16x8_t p8;
#pragma unroll
        for (int j = 0; j < 4; j++) { p8[j] = b0[j]; p8[4 + j] = b1[j]; }
        pf[qa][c] = p8;
      }

#pragma unroll
    for (int qa = 0; qa < 4; qa++)
#pragma unroll
      for (int c = 0; c < 2; c++)
        accL[qa] = mfma16(ones8, pf[qa][c], accL[qa]);

#pragma unroll
    for (int c = 0; c < 2; c++) {
      bf16x8_t va[4];
#pragma unroll
      for (int dm = 0; dm < 4; dm++) {
        const u16* vb = &Vs[kv][buf][(dm * 16 + r) * 64];
        union { uint4 u; bf16x8_t v; } cat;
        *(uint2*)&cat.u.x = *(const uint2*)(vb + vo0[c]);
        *(uint2*)&cat.u.z = *(const uint2*)(vb + vo1[c]);
        va[dm] = cat.v;
      }
      __builtin_amdgcn_s_setprio(1);
#pragma unroll
      for (int qa = 0; qa < 4; qa++)
#pragma unroll
        for (int dm = 0; dm < 4; dm++)
          accO[qa][dm] = mfma16(va[dm], pf[qa][c], accO[qa][dm]);
      __builtin_amdgcn_s_setprio(0);
    }
  }

  __syncthreads();
  float* Sc  = (float*)&Ks[0][0][0];
  float* Lsc = (float*)&Vs[0][0][0];
  if (kv == 1) {
#pragma unroll
    for (int qa = 0; qa < 4; qa++) {
#pragma unroll
      for (int dm = 0; dm < 4; dm++)
        *(f32x4_t*)&Sc[g * 4096 + ((qa * 4 + dm) * 64 + lane) * 4] = accO[qa][dm];
      Lsc[g * 256 + qa * 64 + lane] = accL[qa][0];
    }
  }
  __syncthreads();
  if (kv == 0) {
#pragma unroll
    for (int qa = 0; qa < 4; qa++) {
      float L = accL[qa][0] + Lsc[g * 256 + qa * 64 + lane];
      float inv = 1.f / L;
      int gq = q0 + g * 64 + qa * 16 + r;
#pragma unroll
      for (int dm = 0; dm < 4; dm++) {
        f32x4_t o = *(const f32x4_t*)&Sc[g * 4096 + ((qa * 4 + dm) * 64 + lane) * 4];
        o += accO[qa][dm];
        bf16x4_t ob;
#pragma unroll
        for (int reg = 0; reg < 4; reg++) ob[reg] = (__bf16)(o[reg] * inv);
        *(uint2*)&Oattn[bbase + (long)gq * 512 + h * 64 + dm * 16 + qd * 4] = *(uint2*)&ob;
      }
    }
  }
}

// ---------------- launch ----------------
extern "C" void kernel_launch(void* const* d_in, const int* in_sizes, int n_in,
                              void* d_out, int out_size, void* d_ws, size_t ws_size,
                              hipStream_t stream) {
  const float* x  = (const float*)d_in[0];
  const float* Wq = (const float*)d_in[1];
  const float* Wk = (const float*)d_in[2];
  const float* Wv = (const float*)d_in[3];
  const float* Wo = (const float*)d_in[4];
  const float* bo = (const float*)d_in[5];
  float* out = (float*)d_out;

  u16* ws  = (u16*)d_ws;
  u16* Qb  = ws;
  u16* Kb  = Qb  + 4194304;
  u16* Vtg = Kb  + 4194304;   // V^T: [2*512][4096]
  u16* Ab  = Vtg + 4194304;
  u16* Xb  = Ab;              // aliased: Xb live [cast, qkv); Ab live [attn, out) — disjoint
  u16* Wqb = Ab  + 4194304;
  u16* Wkb = Wqb + 262144;
  u16* Wvb = Wkb + 262144;
  u16* Wob = Wvb + 262144;

  cast_kernel<<<2560, 256, 0, stream>>>(x, Wq, Wk, Wv, Wo, Xb, Wqb, Wkb, Wvb, Wob);

  dim3 g1(128, 4);
  gemm_qkv_fused<<<g1, 512, 0, stream>>>(Xb, Wqb, Wkb, Wvb, Qb, Kb, Vtg);

  dim3 g2(32, 16);
  attn_kernel<<<g2, 256, 0, stream>>>(Qb, Kb, Vtg, Ab);

  dim3 g3(128, 4);
  gemm_out_kernel<<<g3, 512, 0, stream>>>(Ab, Wob, out, bo);
}